// Round 2
// baseline (111.658 us; speedup 1.0000x reference)
//
#include <hip/hip_runtime.h>
#include <math.h>

// Round 2: identical algorithm to round 1 — that round died on container
// acquisition ("MI355X container failed twice"), not on kernel execution.
//
// Algebraic collapse of the reference:
//   G = Hn Hn^T  (Hn = columns of H normalized, viewed as rows of Ht)
//   sum(G)   = || sum_n Hn[n] ||^2   (sum of all pairwise dots = norm^2 of sum)
//   trace(G) = N                      (each row is unit-norm)
//   pair_sum = (sum(G) - N) / 2
//   reg      = pair_sum * 0.5 / (N*(N-1)/2) = (sum(G) - N) * 0.5 / (N*(N-1))
// So: (A) norms2[n] = sum_d H[d][n]^2; (B) s[d] = sum_n H[d][n]/max(sqrt(norms2[n]),eps),
// s2 = sum_d s[d]^2; (C) CE over [B,2] logits; (D) combine.

#define N_COLS  8192   // N: columns of H (rows of Ht)
#define D_ROWS  1024   // D
#define B_ROWS  8192   // batch for CE
#define ROWS_PER_BLOCK 16
#define EPS_NORM 1e-12f

// ---------------------------------------------------------------------------
// Block reduce: 256 threads = 4 waves of 64. Valid result in thread 0.
__device__ inline float block_reduce_sum_256(float v) {
    #pragma unroll
    for (int off = 32; off > 0; off >>= 1) v += __shfl_down(v, off, 64);
    __shared__ float sm[4];
    int lane = threadIdx.x & 63;
    int wid  = threadIdx.x >> 6;
    if (lane == 0) sm[wid] = v;
    __syncthreads();
    if (threadIdx.x < 4) {
        v = sm[threadIdx.x];
        v += __shfl_down(v, 2, 64);
        v += __shfl_down(v, 1, 64);
    }
    return v;
}

// ---------------------------------------------------------------------------
// Kernel A: column sums of squares of H [D, N] (row-major).
// grid = (N/1024, D/ROWS_PER_BLOCK), block = 256; each thread owns 4 columns
// (one float4 lane) over ROWS_PER_BLOCK rows, then 4 atomicAdds.
__global__ __launch_bounds__(256)
void colsumsq_kernel(const float* __restrict__ H, float* __restrict__ norms2) {
    const int col4 = blockIdx.x * blockDim.x + threadIdx.x;   // float4 index
    const int row0 = blockIdx.y * ROWS_PER_BLOCK;
    const float4* __restrict__ H4 = (const float4*)H;
    float ax = 0.f, ay = 0.f, az = 0.f, aw = 0.f;
    #pragma unroll
    for (int r = 0; r < ROWS_PER_BLOCK; ++r) {
        float4 v = H4[(size_t)(row0 + r) * (N_COLS / 4) + col4];
        ax = fmaf(v.x, v.x, ax);
        ay = fmaf(v.y, v.y, ay);
        az = fmaf(v.z, v.z, az);
        aw = fmaf(v.w, v.w, aw);
    }
    const int col = col4 * 4;
    atomicAdd(&norms2[col + 0], ax);
    atomicAdd(&norms2[col + 1], ay);
    atomicAdd(&norms2[col + 2], az);
    atomicAdd(&norms2[col + 3], aw);
}

// ---------------------------------------------------------------------------
// Kernel B: per-row weighted sum  s[d] = sum_n H[d][n] / max(sqrt(norms2[n]), eps),
// then accumulate s[d]^2 into s2_acc. One block per row d.
__global__ __launch_bounds__(256)
void gemv_s2_kernel(const float* __restrict__ H, const float* __restrict__ norms2,
                    float* __restrict__ s2_acc) {
    const int d = blockIdx.x;
    const float4* __restrict__ Hrow = (const float4*)(H + (size_t)d * N_COLS);
    const float4* __restrict__ n24  = (const float4*)norms2;
    float acc = 0.f;
    #pragma unroll 4
    for (int i = threadIdx.x; i < N_COLS / 4; i += 256) {
        float4 v  = Hrow[i];
        float4 n2 = n24[i];
        float wx = 1.f / fmaxf(sqrtf(n2.x), EPS_NORM);
        float wy = 1.f / fmaxf(sqrtf(n2.y), EPS_NORM);
        float wz = 1.f / fmaxf(sqrtf(n2.z), EPS_NORM);
        float ww = 1.f / fmaxf(sqrtf(n2.w), EPS_NORM);
        acc = fmaf(v.x, wx, acc);
        acc = fmaf(v.y, wy, acc);
        acc = fmaf(v.z, wz, acc);
        acc = fmaf(v.w, ww, acc);
    }
    float s = block_reduce_sum_256(acc);
    if (threadIdx.x == 0) atomicAdd(s2_acc, s * s);
}

// ---------------------------------------------------------------------------
// Kernel C: cross-entropy over [B, 2] logits; sum of per-row NLL into ce_acc.
__global__ __launch_bounds__(256)
void ce_kernel(const float* __restrict__ logits, const int* __restrict__ labels,
               float* __restrict__ ce_acc) {
    const int b = blockIdx.x * blockDim.x + threadIdx.x;   // grid exactly covers B
    float2 x = ((const float2*)logits)[b];
    float m = fmaxf(x.x, x.y);
    float lse = m + logf(expf(x.x - m) + expf(x.y - m));
    int lab = labels[b];
    float xl = (lab == 0) ? x.x : x.y;
    float nll = lse - xl;
    float s = block_reduce_sum_256(nll);
    if (threadIdx.x == 0) atomicAdd(ce_acc, s);
}

// ---------------------------------------------------------------------------
// Kernel D: combine:  out = ce_mean + (s2 - N) * LAMBDA / (N*(N-1))
// (pair_sum = (s2 - N)/2; reg = pair_sum * LAMBDA / (N*(N-1)/2), LAMBDA=0.5)
__global__ void finalize_kernel(const float* __restrict__ s2_acc,
                                const float* __restrict__ ce_acc,
                                float* __restrict__ out) {
    double s2 = (double)s2_acc[0];
    double reg = (s2 - (double)N_COLS) * 0.5 / ((double)N_COLS * (double)(N_COLS - 1));
    double ce = (double)ce_acc[0] / (double)B_ROWS;
    out[0] = (float)(ce + reg);
}

// ---------------------------------------------------------------------------
extern "C" void kernel_launch(void* const* d_in, const int* in_sizes, int n_in,
                              void* d_out, int out_size, void* d_ws, size_t ws_size,
                              hipStream_t stream) {
    const float* outputs = (const float*)d_in[0];   // [B, 2] f32
    const int*   labels  = (const int*)d_in[1];     // [B] int
    const float* H       = (const float*)d_in[2];   // [D, N] f32
    float* out = (float*)d_out;

    // ws layout: norms2[N] | s2_acc | ce_acc
    float* norms2 = (float*)d_ws;
    float* s2_acc = norms2 + N_COLS;
    float* ce_acc = s2_acc + 1;

    // zero the accumulators (ws is poisoned 0xAA before every timed launch)
    hipMemsetAsync(d_ws, 0, (N_COLS + 2) * sizeof(float), stream);

    colsumsq_kernel<<<dim3(N_COLS / 1024, D_ROWS / ROWS_PER_BLOCK), 256, 0, stream>>>(H, norms2);
    gemv_s2_kernel<<<D_ROWS, 256, 0, stream>>>(H, norms2, s2_acc);
    ce_kernel<<<B_ROWS / 256, 256, 0, stream>>>(outputs, labels, ce_acc);
    finalize_kernel<<<1, 1, 0, stream>>>(s2_acc, ce_acc, out);
}